// Round 1
// baseline (375.526 us; speedup 1.0000x reference)
//
#include <hip/hip_runtime.h>

#define B_ 32
#define S_ 8192
#define H_ 256

// ---------------------------------------------------------------------------
// Kernel 1: v[b,d] = sum_e h_d_t[b,e] * W[e,d]
// Split the e-dimension over 8 chunks (grid.y) so we get 256 blocks instead of
// a latency-bound 32-block launch. Partials combined via atomicAdd (v zeroed
// by the memset in kernel_launch).
// ---------------------------------------------------------------------------
__global__ __launch_bounds__(256) void gemv_hdtW(
    const float* __restrict__ hdt,  // (B, H)
    const float* __restrict__ W,    // (H, H) row-major [e][d]
    float* __restrict__ v)          // (B, H), pre-zeroed
{
    const int b  = blockIdx.x;
    const int ec = blockIdx.y;          // 8 chunks of 32 e-values
    const int d  = threadIdx.x;         // 256

    __shared__ float lh[32];
    if (d < 32) lh[d] = hdt[b * H_ + ec * 32 + d];
    __syncthreads();

    float acc = 0.f;
    const float* Wp = W + (size_t)(ec * 32) * H_ + d;   // coalesced across d
#pragma unroll
    for (int e = 0; e < 32; ++e) acc = fmaf(lh[e], Wp[(size_t)e * H_], acc);

    atomicAdd(&v[b * H_ + d], acc);
}

// ---------------------------------------------------------------------------
// Kernel 2: single pass over h_enc.
// One wave per s: lane l holds elements [4l,4l+4) of both v and h_enc[b,s].
//   dot -> wave shfl_xor reduce -> exp -> att_un = exp/sum_exp * mask
// Writes unnormalized alphat + new_sum, accumulates denom[b] and
// ct_un[b,:] (block LDS reduce, then one global atomicAdd per element).
// ---------------------------------------------------------------------------
__global__ __launch_bounds__(256) void attn_main(
    const float* __restrict__ v,        // (B, H)
    const float* __restrict__ h_enc,    // (B, S, H)
    const float* __restrict__ sum_exp,  // (B, S)
    const float* __restrict__ mask,     // (B, S)
    float* __restrict__ out_alphat,     // (B, S)  (unnormalized for now)
    float* __restrict__ out_newsum,     // (B, S)
    float* __restrict__ denom,          // (B), pre-zeroed
    float* __restrict__ ct_un)          // (B, H), pre-zeroed
{
    constexpr int WAVES = 4;
    constexpr int SPB   = S_ / 32;      // 256 s-values per block, grid.x = 32

    const int b    = blockIdx.y;
    const int tid  = threadIdx.x;
    const int lane = tid & 63;
    const int wave = tid >> 6;
    const int s0   = blockIdx.x * SPB;

    const float4 vf = reinterpret_cast<const float4*>(v + b * H_)[lane];

    const float* __restrict__ hb  = h_enc  + (size_t)b * S_ * H_;
    const float* __restrict__ seb = sum_exp + (size_t)b * S_;
    const float* __restrict__ mkb = mask    + (size_t)b * S_;
    float* __restrict__ oab = out_alphat + (size_t)b * S_;
    float* __restrict__ onb = out_newsum + (size_t)b * S_;

    float4 ct  = {0.f, 0.f, 0.f, 0.f};
    float  den = 0.f;

    for (int i = 0; i < SPB / WAVES; ++i) {
        const int s = s0 + wave + WAVES * i;   // 4 waves interleaved in s
        const float4 hf = reinterpret_cast<const float4*>(hb + (size_t)s * H_)[lane];

        float dot = fmaf(vf.x, hf.x, fmaf(vf.y, hf.y, fmaf(vf.z, hf.z, vf.w * hf.w)));
#pragma unroll
        for (int off = 32; off; off >>= 1) dot += __shfl_xor(dot, off, 64);

        const float se  = seb[s];              // broadcast load (all lanes same addr)
        const float e   = __expf(dot);
        const float att = e / se * mkb[s];

        if (lane == 0) {
            oab[s] = att;                      // unnormalized; finalize divides
            onb[s] = se + e;
        }
        den += att;
        ct.x = fmaf(att, hf.x, ct.x);
        ct.y = fmaf(att, hf.y, ct.y);
        ct.z = fmaf(att, hf.z, ct.z);
        ct.w = fmaf(att, hf.w, ct.w);
    }

    // Block reduce: 4 waves x 256 elements -> 256, then one atomic per element.
    __shared__ __align__(16) float lct[WAVES * H_];   // 4 KiB
    __shared__ float lden[WAVES];
    reinterpret_cast<float4*>(lct + wave * H_)[lane] = ct;
    if (lane == 0) lden[wave] = den;
    __syncthreads();

    const float s4 = lct[tid] + lct[H_ + tid] + lct[2 * H_ + tid] + lct[3 * H_ + tid];
    atomicAdd(&ct_un[b * H_ + tid], s4);
    if (tid == 0) atomicAdd(&denom[b], lden[0] + lden[1] + lden[2] + lden[3]);
}

// ---------------------------------------------------------------------------
// Kernel 3: divide ct_un and alphat by denom[b].
// idx in [0, B*H) -> ct_e; idx in [B*H, B*H + B*S) -> alphat scale-in-place.
// ---------------------------------------------------------------------------
__global__ __launch_bounds__(256) void finalize(
    const float* __restrict__ denom,
    const float* __restrict__ ct_un,
    float* __restrict__ out_ct,
    float* __restrict__ out_alphat)
{
    const int idx = blockIdx.x * blockDim.x + threadIdx.x;
    if (idx < B_ * H_) {
        out_ct[idx] = ct_un[idx] / denom[idx >> 8];        // /256
    } else {
        const int p = idx - B_ * H_;
        if (p < B_ * S_) {
            out_alphat[p] = out_alphat[p] / denom[p >> 13]; // /8192
        }
    }
}

extern "C" void kernel_launch(void* const* d_in, const int* in_sizes, int n_in,
                              void* d_out, int out_size, void* d_ws, size_t ws_size,
                              hipStream_t stream) {
    const float* h_d_t   = (const float*)d_in[0];   // (B, H)
    const float* h_enc   = (const float*)d_in[1];   // (B, S, H)
    const float* mask    = (const float*)d_in[2];   // (B, S)
    const float* sum_exp = (const float*)d_in[3];   // (B, S)
    const float* W       = (const float*)d_in[4];   // (H, H)

    float* out        = (float*)d_out;
    float* out_ct     = out;                        // (B, H)
    float* out_alphat = out + B_ * H_;              // (B, S)
    float* out_newsum = out + B_ * H_ + B_ * S_;    // (B, S)

    // ws layout: [denom: B][ct_un: B*H][v: B*H] -- all need zeroing
    float* ws    = (float*)d_ws;
    float* denom = ws;
    float* ct_un = ws + B_;
    float* v     = ws + B_ + B_ * H_;
    hipMemsetAsync(d_ws, 0, (size_t)(B_ + 2 * B_ * H_) * sizeof(float), stream);

    gemv_hdtW<<<dim3(B_, 8), 256, 0, stream>>>(h_d_t, W, v);
    attn_main<<<dim3(32, B_), 256, 0, stream>>>(v, h_enc, sum_exp, mask,
                                                out_alphat, out_newsum, denom, ct_un);
    const int fin_n = B_ * H_ + B_ * S_;            // 270336
    finalize<<<(fin_n + 255) / 256, 256, 0, stream>>>(denom, ct_un, out_ct, out_alphat);
}

// Round 2
// 374.838 us; speedup vs baseline: 1.0018x; 1.0018x over previous
//
#include <hip/hip_runtime.h>

#define B_ 32
#define S_ 8192
#define H_ 256

#define SPB 128          // s-rows per attn block (grid.x = S_/SPB = 64)

// ---------------------------------------------------------------------------
// Kernel 1: v[b,d] = sum_e h_d_t[b,e] * W[e,d]   (unchanged from R1 - proven)
// ---------------------------------------------------------------------------
__global__ __launch_bounds__(256) void gemv_hdtW(
    const float* __restrict__ hdt,  // (B, H)
    const float* __restrict__ W,    // (H, H) row-major [e][d]
    float* __restrict__ v)          // (B, H), pre-zeroed
{
    const int b  = blockIdx.x;
    const int ec = blockIdx.y;          // 8 chunks of 32 e-values
    const int d  = threadIdx.x;         // 256

    __shared__ float lh[32];
    if (d < 32) lh[d] = hdt[b * H_ + ec * 32 + d];
    __syncthreads();

    float acc = 0.f;
    const float* Wp = W + (size_t)(ec * 32) * H_ + d;   // coalesced across d
#pragma unroll
    for (int e = 0; e < 32; ++e) acc = fmaf(lh[e], Wp[(size_t)e * H_], acc);

    atomicAdd(&v[b * H_ + d], acc);
}

// ---------------------------------------------------------------------------
// Kernel 2: single pass over h_enc, 16-lanes-per-row layout.
// Wave = 4 groups x 16 lanes; group g handles one row per iteration.
// Lane (sub = lane&15) holds float4 columns {(j*16+sub)*4 .. +4}, j=0..3,
// of both v and the row -> 16 in-lane MACs, then a 4-step width-16
// butterfly reduces all 4 rows' dots at once (1 shfl/row vs 6 in R1).
// sum_exp/mask staged in LDS as a precomputed multiplier (no per-row div,
// no per-row broadcast VMEM). alphat/new_sum staged in LDS, stored
// coalesced in the epilogue.
// ---------------------------------------------------------------------------
__global__ __launch_bounds__(256, 5) void attn_main(
    const float* __restrict__ v,        // (B, H)
    const float* __restrict__ h_enc,    // (B, S, H)
    const float* __restrict__ sum_exp,  // (B, S)
    const float* __restrict__ mask,     // (B, S)
    float* __restrict__ out_alphat,     // (B, S)  (unnormalized; finalize divides)
    float* __restrict__ out_newsum,     // (B, S)
    float* __restrict__ denom,          // (B), pre-zeroed
    float* __restrict__ ct_un)          // (B, H), pre-zeroed
{
    const int b    = blockIdx.y;
    const int tid  = threadIdx.x;
    const int lane = tid & 63;
    const int wave = tid >> 6;          // 0..3
    const int sub  = lane & 15;         // lane within 16-lane group
    const int grp  = lane >> 4;         // 0..3
    const int pid  = wave * 4 + grp;    // partial id 0..15
    const int s0   = blockIdx.x * SPB;

    __shared__ float lmult[SPB];        // mask/se
    __shared__ float lse[SPB];          // se (for new_sum)
    __shared__ float lalpha[SPB];
    __shared__ float lnew[SPB];
    __shared__ __align__(16) float lct[16][H_];   // 16 KiB
    __shared__ float lden[16];

    // Stage se/mask -> multiplier (one divide per row per BLOCK, not per wave-iter)
    if (tid < SPB) {
        const float se = sum_exp[(size_t)b * S_ + s0 + tid];
        const float mk = mask[(size_t)b * S_ + s0 + tid];
        lse[tid]   = se;
        lmult[tid] = mk / se;
    }
    __syncthreads();

    // v fragment: 4 float4s at float4-index j*16+sub
    const float4* v4 = reinterpret_cast<const float4*>(v + b * H_);
    const float4 vf0 = v4[0 * 16 + sub];
    const float4 vf1 = v4[1 * 16 + sub];
    const float4 vf2 = v4[2 * 16 + sub];
    const float4 vf3 = v4[3 * 16 + sub];

    const float* __restrict__ hb = h_enc + (size_t)b * S_ * H_;

    float4 ct0 = {0.f,0.f,0.f,0.f}, ct1 = {0.f,0.f,0.f,0.f};
    float4 ct2 = {0.f,0.f,0.f,0.f}, ct3 = {0.f,0.f,0.f,0.f};
    float  den = 0.f;

#pragma unroll 2
    for (int i = 0; i < SPB / 16; ++i) {          // 8 iterations
        const int lr = i * 16 + wave * 4 + grp;   // local row for this group
        const float4* h4 = reinterpret_cast<const float4*>(hb + (size_t)(s0 + lr) * H_);
        const float4 h0 = h4[0 * 16 + sub];
        const float4 h1 = h4[1 * 16 + sub];
        const float4 h2 = h4[2 * 16 + sub];
        const float4 h3 = h4[3 * 16 + sub];

        float dot;
        dot = fmaf(vf0.x, h0.x, fmaf(vf0.y, h0.y, fmaf(vf0.z, h0.z, vf0.w * h0.w)));
        dot = fmaf(vf1.x, h1.x, fmaf(vf1.y, h1.y, fmaf(vf1.z, h1.z, fmaf(vf1.w, h1.w, dot))));
        dot = fmaf(vf2.x, h2.x, fmaf(vf2.y, h2.y, fmaf(vf2.z, h2.z, fmaf(vf2.w, h2.w, dot))));
        dot = fmaf(vf3.x, h3.x, fmaf(vf3.y, h3.y, fmaf(vf3.z, h3.z, fmaf(vf3.w, h3.w, dot))));

        // width-16 butterfly: reduces all 4 groups' rows simultaneously
        dot += __shfl_xor(dot, 1, 16);
        dot += __shfl_xor(dot, 2, 16);
        dot += __shfl_xor(dot, 4, 16);
        dot += __shfl_xor(dot, 8, 16);

        const float e   = __expf(dot);
        const float att = e * lmult[lr];          // LDS broadcast, no div
        if (sub == 0) {
            lalpha[lr] = att;
            lnew[lr]   = lse[lr] + e;
        }
        den += att;
        ct0.x = fmaf(att, h0.x, ct0.x); ct0.y = fmaf(att, h0.y, ct0.y);
        ct0.z = fmaf(att, h0.z, ct0.z); ct0.w = fmaf(att, h0.w, ct0.w);
        ct1.x = fmaf(att, h1.x, ct1.x); ct1.y = fmaf(att, h1.y, ct1.y);
        ct1.z = fmaf(att, h1.z, ct1.z); ct1.w = fmaf(att, h1.w, ct1.w);
        ct2.x = fmaf(att, h2.x, ct2.x); ct2.y = fmaf(att, h2.y, ct2.y);
        ct2.z = fmaf(att, h2.z, ct2.z); ct2.w = fmaf(att, h2.w, ct2.w);
        ct3.x = fmaf(att, h3.x, ct3.x); ct3.y = fmaf(att, h3.y, ct3.y);
        ct3.z = fmaf(att, h3.z, ct3.z); ct3.w = fmaf(att, h3.w, ct3.w);
    }

    // Block reduce: 16 partial-ct's (one per wave x group) -> 256 columns
    float4* dst = reinterpret_cast<float4*>(&lct[pid][0]);
    dst[0 * 16 + sub] = ct0;
    dst[1 * 16 + sub] = ct1;
    dst[2 * 16 + sub] = ct2;
    dst[3 * 16 + sub] = ct3;
    if (sub == 0) lden[pid] = den;    // den duplicated across the 16 lanes
    __syncthreads();

    float tot = 0.f;
#pragma unroll
    for (int p = 0; p < 16; ++p) tot += lct[p][tid];
    atomicAdd(&ct_un[b * H_ + tid], tot);

    if (tid == 0) {
        float d = 0.f;
#pragma unroll
        for (int p = 0; p < 16; ++p) d += lden[p];
        atomicAdd(&denom[b], d);
    }

    // Coalesced epilogue stores for alphat (unnormalized) and new_sum
    if (tid < SPB) {
        out_alphat[(size_t)b * S_ + s0 + tid] = lalpha[tid];
        out_newsum[(size_t)b * S_ + s0 + tid] = lnew[tid];
    }
}

// ---------------------------------------------------------------------------
// Kernel 3: divide ct_un and alphat by denom[b].
// ---------------------------------------------------------------------------
__global__ __launch_bounds__(256) void finalize(
    const float* __restrict__ denom,
    const float* __restrict__ ct_un,
    float* __restrict__ out_ct,
    float* __restrict__ out_alphat)
{
    const int idx = blockIdx.x * blockDim.x + threadIdx.x;
    if (idx < B_ * H_) {
        out_ct[idx] = ct_un[idx] / denom[idx >> 8];        // /256
    } else {
        const int p = idx - B_ * H_;
        if (p < B_ * S_) {
            out_alphat[p] = out_alphat[p] / denom[p >> 13]; // /8192
        }
    }
}

extern "C" void kernel_launch(void* const* d_in, const int* in_sizes, int n_in,
                              void* d_out, int out_size, void* d_ws, size_t ws_size,
                              hipStream_t stream) {
    const float* h_d_t   = (const float*)d_in[0];   // (B, H)
    const float* h_enc   = (const float*)d_in[1];   // (B, S, H)
    const float* mask    = (const float*)d_in[2];   // (B, S)
    const float* sum_exp = (const float*)d_in[3];   // (B, S)
    const float* W       = (const float*)d_in[4];   // (H, H)

    float* out        = (float*)d_out;
    float* out_ct     = out;                        // (B, H)
    float* out_alphat = out + B_ * H_;              // (B, S)
    float* out_newsum = out + B_ * H_ + B_ * S_;    // (B, S)

    // ws layout: [denom: B][ct_un: B*H][v: B*H] -- all need zeroing
    float* ws    = (float*)d_ws;
    float* denom = ws;
    float* ct_un = ws + B_;
    float* v     = ws + B_ + B_ * H_;
    hipMemsetAsync(d_ws, 0, (size_t)(B_ + 2 * B_ * H_) * sizeof(float), stream);

    gemv_hdtW<<<dim3(B_, 8), 256, 0, stream>>>(h_d_t, W, v);
    attn_main<<<dim3(S_ / SPB, B_), 256, 0, stream>>>(v, h_enc, sum_exp, mask,
                                                      out_alphat, out_newsum, denom, ct_un);
    const int fin_n = B_ * H_ + B_ * S_;            // 270336
    finalize<<<(fin_n + 255) / 256, 256, 0, stream>>>(denom, ct_un, out_ct, out_alphat);
}